// Round 2
// baseline (14080.495 us; speedup 1.0000x reference)
//
#include <hip/hip_runtime.h>
#include <hip/hip_bf16.h>
#include <stdint.h>

#define T_STEPS 256
#define BATCH   64
#define HID     512
#define HALF    256
#define NCOLS   1536              // [zr1:512 | g1:256 | zr2:512 | g2:256]
#define MROWS   (T_STEPS * BATCH) // 16384
#define SLICE_N 100
#define SAVED_OFF (2 * BATCH * HID) // 65536 floats into d_out

// swizzled weight stream: per layer, 49152 fragments of 16B:
//   stage0 zr1: frags [0,16384)        (w:16, idx:16, lane:64)
//   stage1 g1 : frags [16384,24576)    (w:16, idx:8,  lane:64)
//   stage2 zr2: frags [24576,40960)
//   stage3 g2 : frags [40960,49152)
#define SB0 0
#define SB1 16384
#define SB2 24576
#define SB3 40960
#define FRAGS_PER_LAYER 49152

typedef short bf16x8 __attribute__((ext_vector_type(8)));
typedef float f32x4  __attribute__((ext_vector_type(4)));

__device__ __forceinline__ f32x4 mfma16(bf16x8 a, bf16x8 b, f32x4 c) {
  return __builtin_amdgcn_mfma_f32_16x16x32_bf16(a, b, c, 0, 0, 0);
}
__device__ __forceinline__ float sigm_f(float x) {
  return 1.f / (1.f + __expf(-x));
}
__device__ __forceinline__ float tanh_f(float x) {
  x = fminf(fmaxf(x, -30.f), 30.f);
  float e = __expf(-2.f * x);
  return (1.f - e) / (1.f + e);
}

struct AllW {
  const float* W[8]; // l0: zr1,g1,zr2,g2 ; l1: zr1,g1,zr2,g2
  const float* b[8];
};

// ---------------------------------------------------------------- prep
// Builds: Wsw (swizzled recurrent-frag stream, bf16), WxT ([l][1536][512] bf16),
// biasAll ([l][1536] f32).
__global__ void prep_weights(AllW aw, __hip_bfloat16* __restrict__ Wsw,
                             __hip_bfloat16* __restrict__ WxT,
                             float* __restrict__ biasAll) {
  int tid = blockIdx.x * blockDim.x + threadIdx.x;
  const int NW = 2 * FRAGS_PER_LAYER;          // 98304 fragment threads
  const int NX = 2 * NCOLS * 64;               // 196608 WxT threads (8 elems each)
  if (tid < NW) {
    int l = tid / FRAGS_PER_LAYER, r = tid % FRAGS_PER_LAYER;
    int s, fi;
    if (r < SB1)      { s = 0; fi = r; }
    else if (r < SB2) { s = 1; fi = r - SB1; }
    else if (r < SB3) { s = 2; fi = r - SB2; }
    else              { s = 3; fi = r - SB3; }
    int lane = fi & 63, lrow = lane & 15, lgrp = lane >> 4;
    int zr = (s == 0 || s == 2);
    int w   = zr ? (fi >> 10) : (fi >> 9);
    int idx = zr ? ((fi >> 6) & 15) : ((fi >> 6) & 7);
    int col, kt;
    if (zr) { kt = idx >> 1; col = w * 32 + (idx & 1) * 16 + lrow; }
    else    { kt = idx;      col = w * 16 + lrow; }
    const float* W = aw.W[l * 4 + s];
    int nc = zr ? 512 : 256;
    int kbase = 512 + kt * 32 + lgrp * 8;
    __hip_bfloat16 frag[8];
#pragma unroll
    for (int e = 0; e < 8; ++e)
      frag[e] = __float2bfloat16(W[(size_t)(kbase + e) * nc + col]);
    *(uint4*)&Wsw[(size_t)tid * 8] = *(uint4*)frag;
  } else if (tid < NW + NX) {
    int u = tid - NW;
    int l = u / (NCOLS * 64), r = u % (NCOLS * 64);
    int c = r >> 6, k0 = (r & 63) * 8;
    const float* W; int nc, cc;
    if (c < 512)       { W = aw.W[l*4+0]; nc = 512; cc = c;        }
    else if (c < 768)  { W = aw.W[l*4+1]; nc = 256; cc = c - 512;  }
    else if (c < 1280) { W = aw.W[l*4+2]; nc = 512; cc = c - 768;  }
    else               { W = aw.W[l*4+3]; nc = 256; cc = c - 1280; }
    __hip_bfloat16 frag[8];
#pragma unroll
    for (int e = 0; e < 8; ++e)
      frag[e] = __float2bfloat16(W[(size_t)(k0 + e) * nc + cc]);
    *(uint4*)&WxT[((size_t)l * NCOLS + c) * 512 + k0] = *(uint4*)frag;
  } else if (tid < NW + NX + 2 * NCOLS) {
    int c = tid - NW - NX;
    int l = c / NCOLS, cc = c % NCOLS;
    const float* b; int off;
    if (cc < 512)       { b = aw.b[l*4+0]; off = cc;        }
    else if (cc < 768)  { b = aw.b[l*4+1]; off = cc - 512;  }
    else if (cc < 1280) { b = aw.b[l*4+2]; off = cc - 768;  }
    else                { b = aw.b[l*4+3]; off = cc - 1280; }
    biasAll[c] = b[off];
  }
}

// ---------------------------------------------------------------- embed gather
__global__ void embed_gather(const int* __restrict__ seq, const float* __restrict__ emb,
                             __hip_bfloat16* __restrict__ X0) {
  int i = blockIdx.x * blockDim.x + threadIdx.x; // over 16384*128
  int row = i >> 7, c4 = (i & 127) * 4;
  int idx = seq[row];
  float4 v = *(const float4*)&emb[(size_t)idx * HID + c4];
  union { __hip_bfloat16 h[4]; uint2 u; } pk;
  pk.h[0] = __float2bfloat16(v.x);
  pk.h[1] = __float2bfloat16(v.y);
  pk.h[2] = __float2bfloat16(v.z);
  pk.h[3] = __float2bfloat16(v.w);
  *(uint2*)&X0[(size_t)row * HID + c4] = pk.u;
}

// ---------------------------------------------------------------- P_sw = A @ WxT^T + bias
// A: [16384][512] bf16. WT: [1536][512] bf16. Output swizzled:
// P_sw[g:4][t:256][jg:6][w:16][lane:64][rr:4] f32 where
//   jg0/1 = zr1 nt0/1, jg2 = g1, jg3/4 = zr2 nt0/1, jg5 = g2.
__global__ __launch_bounds__(256) void gemm_p(const __hip_bfloat16* __restrict__ A,
                                              const __hip_bfloat16* __restrict__ WT,
                                              const float* __restrict__ bias,
                                              float* __restrict__ Psw) {
  const int tid = threadIdx.x;
  const int lane = tid & 63, w = tid >> 6;
  const int lrow = lane & 15, lgrp = lane >> 4;
  const int n0 = blockIdx.x * 64, m0 = blockIdx.y * 64;
  const int wm = w & 1, wn = w >> 1;
  __shared__ __hip_bfloat16 As[64][72];
  f32x4 acc[2][2];
#pragma unroll
  for (int a = 0; a < 2; ++a)
#pragma unroll
    for (int b = 0; b < 2; ++b) acc[a][b] = (f32x4){0.f, 0.f, 0.f, 0.f};

  const int lr = tid >> 2, lc = (tid & 3) * 16;
  for (int k0 = 0; k0 < 512; k0 += 64) {
    *(uint4*)&As[lr][lc]     = *(const uint4*)&A[((size_t)m0 + lr) * 512 + k0 + lc];
    *(uint4*)&As[lr][lc + 8] = *(const uint4*)&A[((size_t)m0 + lr) * 512 + k0 + lc + 8];
    __syncthreads();
#pragma unroll
    for (int kt = 0; kt < 2; ++kt) {
      bf16x8 a0 = *(const bf16x8*)&As[wm * 32 + lrow][kt * 32 + lgrp * 8];
      bf16x8 a1 = *(const bf16x8*)&As[wm * 32 + 16 + lrow][kt * 32 + lgrp * 8];
      bf16x8 b0 = *(const bf16x8*)&WT[((size_t)n0 + wn * 32 + lrow) * 512 + k0 + kt * 32 + lgrp * 8];
      bf16x8 b1 = *(const bf16x8*)&WT[((size_t)n0 + wn * 32 + 16 + lrow) * 512 + k0 + kt * 32 + lgrp * 8];
      acc[0][0] = mfma16(a0, b0, acc[0][0]);
      acc[0][1] = mfma16(a0, b1, acc[0][1]);
      acc[1][0] = mfma16(a1, b0, acc[1][0]);
      acc[1][1] = mfma16(a1, b1, acc[1][1]);
    }
    __syncthreads();
  }
  const int t = m0 >> 6;
#pragma unroll
  for (int mt = 0; mt < 2; ++mt) {
    int g = wm * 2 + mt;
#pragma unroll
    for (int nt = 0; nt < 2; ++nt) {
      int colb = n0 + wn * 32 + nt * 16; // wave-uniform
      int jg, wr;
      if (colb < 512)       { jg = (colb >> 4) & 1; wr = colb >> 5; }
      else if (colb < 768)  { jg = 2; wr = (colb - 512) >> 4; }
      else if (colb < 1280) { int c2 = colb - 768; jg = 3 + ((c2 >> 4) & 1); wr = c2 >> 5; }
      else                  { jg = 5; wr = (colb - 1280) >> 4; }
      float bv = bias[colb + lrow];
      float4 v;
      v.x = acc[mt][nt][0] + bv;
      v.y = acc[mt][nt][1] + bv;
      v.z = acc[mt][nt][2] + bv;
      v.w = acc[mt][nt][3] + bv;
      size_t off = ((((size_t)g * 256 + t) * 6 + jg) * 16 + wr) * 256 + (size_t)lane * 4;
      *(float4*)&Psw[off] = v;
    }
  }
}

// ---------------------------------------------------------------- recurrence
// 4 WGs x 16 batch rows x 16 waves. Weight frag stream reloaded from L2 each
// stage via coalesced dwordx4 into a rolling register window (fz[16], fg[8]).
template <int LAYER>
__global__ __launch_bounds__(1024) void rec_kernel(
    const __hip_bfloat16* __restrict__ WswL,
    const float* __restrict__ PswAll,
    float* __restrict__ out,
    __hip_bfloat16* __restrict__ Hseq) {
  const int tid = threadIdx.x;
  const int lane = tid & 63, w = tid >> 6;
  const int lrow = lane & 15, lgrp = lane >> 4;
  const int g4 = blockIdx.x;
  const int b0 = g4 * 16;

  // master f32 state + z staging
  __shared__ float h1f[16][257], h2f[16][257], zf[16][257];
  // bf16 A-operand buffers, fragment-major: elem(row,k) at ((k>>3)*16+row)*8+(k&7)
  __shared__ __hip_bfloat16 h1b[4096], h2b[4096], agb[4096];

  {
    __hip_bfloat16 z0 = __float2bfloat16(0.f);
    for (int i = tid; i < 4096; i += 1024) { h1b[i] = z0; h2b[i] = z0; }
    float* f1 = &h1f[0][0]; float* f2 = &h2f[0][0];
    for (int i = tid; i < 16 * 257; i += 1024) { f1[i] = 0.f; f2[i] = 0.f; }
    if (LAYER == 1) {
      for (int i = tid; i < 16 * SLICE_N; i += 1024)
        out[SAVED_OFF + (size_t)(b0 + i / SLICE_N) * SLICE_N + (i % SLICE_N)] = 0.f;
    }
  }

  const bf16x8* Wf = (const bf16x8*)WswL;
  const bf16x8* pz1 = Wf + SB0 + (size_t)w * 16 * 64 + lane;
  const bf16x8* pg1 = Wf + SB1 + (size_t)w * 8 * 64 + lane;
  const bf16x8* pz2 = Wf + SB2 + (size_t)w * 16 * 64 + lane;
  const bf16x8* pg2 = Wf + SB3 + (size_t)w * 8 * 64 + lane;

  const float* Psw = PswAll + (size_t)g4 * 256 * 6 * 16 * 256;
  auto loadPj = [&](int t, int jg) -> float4 {
    return *(const float4*)&Psw[(((size_t)t * 6 + jg) * 16 + w) * 256 + (size_t)lane * 4];
  };

  // bootstrap: stage-1 / stage-2 fragments + stage-1 P
  bf16x8 fz[16], fg[8];
#pragma unroll
  for (int i = 0; i < 16; ++i) fz[i] = pz1[i * 64];
#pragma unroll
  for (int i = 0; i < 8; ++i)  fg[i] = pg1[i * 64];
  float4 pA = loadPj(0, 0), pB = loadPj(0, 1);
  float4 pG, pC0, pC1, pH;
  __syncthreads();

  const float Q23 = 8388608.f, IQ23 = 1.f / 8388608.f;
  const float Q10 = 1024.f,    IQ10 = 1.f / 1024.f;

  for (int t = 0; t < T_STEPS; ++t) {
    const int tn = (t + 1 < T_STEPS) ? (t + 1) : (T_STEPS - 1);
    // ================= stage 1: zr1 = sigma(P + h2 @ Uzr1)
    {
      pG = loadPj(t, 2); // prefetch stage-2 P
      f32x4 a0 = (f32x4){0.f,0.f,0.f,0.f}, a1 = (f32x4){0.f,0.f,0.f,0.f};
      const bf16x8* ab = (const bf16x8*)h2b;
#pragma unroll
      for (int kt = 0; kt < 8; ++kt) {
        bf16x8 A = ab[kt * 64 + lane];
        a0 = mfma16(A, fz[2 * kt], a0);
        a1 = mfma16(A, fz[2 * kt + 1], a1);
        fz[2 * kt]     = pz2[(2 * kt) * 64];     // reload -> stage-3 frags
        fz[2 * kt + 1] = pz2[(2 * kt + 1) * 64];
      }
#pragma unroll
      for (int nt = 0; nt < 2; ++nt) {
        float4 pp = nt ? pB : pA;
        f32x4 ac = nt ? a1 : a0;
        if (w < 8) {
          int col = w * 32 + nt * 16 + lrow;
#pragma unroll
          for (int rr = 0; rr < 4; ++rr)
            zf[lgrp * 4 + rr][col] = 0.875f * sigm_f(ac[rr] + pp[rr]) + 0.125f;
        } else {
          int col = (w - 8) * 32 + nt * 16 + lrow;
          int fo = (col >> 3) * 16, fe = col & 7;
#pragma unroll
          for (int rr = 0; rr < 4; ++rr) {
            int row = lgrp * 4 + rr;
            float r1 = sigm_f(ac[rr] + pp[rr]);
            float h2v = __bfloat162float(h2b[(fo + row) * 8 + fe]);
            agb[(fo + row) * 8 + fe] = __float2bfloat16(r1 * h2v);
          }
        }
      }
    }
    __syncthreads();

    // ================= stage 2: g1 = tanh(P + agb @ Ug1); h1 update
    {
      pC0 = loadPj(t, 3); pC1 = loadPj(t, 4); // prefetch stage-3 P
      f32x4 a2 = (f32x4){0.f,0.f,0.f,0.f};
      const bf16x8* ab = (const bf16x8*)agb;
#pragma unroll
      for (int kt = 0; kt < 8; ++kt) {
        bf16x8 A = ab[kt * 64 + lane];
        a2 = mfma16(A, fg[kt], a2);
        fg[kt] = pg2[kt * 64]; // reload -> stage-4 frags
      }
      int col = w * 16 + lrow;
      int fo = (col >> 3) * 16, fe = col & 7;
#pragma unroll
      for (int rr = 0; rr < 4; ++rr) {
        int row = lgrp * 4 + rr;
        float gv = tanh_f(a2[rr] + pG[rr]);
        float z  = zf[row][col];
        float zq = floorf(z * Q10) * IQ10;
        float h  = h1f[row][col];
        h = floorf(h * zq * Q23) * IQ23;
        h = h + rintf((1.f - z) * gv * Q23) * IQ23;
        h1f[row][col] = h;
        h1b[(fo + row) * 8 + fe] = __float2bfloat16(h);
        if (LAYER == 0)
          Hseq[((size_t)t * BATCH + b0 + row) * HID + col] = __float2bfloat16(h);
        if (LAYER == 1 && col < SLICE_N)
          out[SAVED_OFF + (size_t)(t + 1) * (BATCH * SLICE_N) + (b0 + row) * SLICE_N + col] = h;
        if (t == T_STEPS - 1)
          out[(size_t)LAYER * (BATCH * HID) + (b0 + row) * HID + col] = h;
      }
    }
    __syncthreads();

    // ================= stage 3: zr2 = sigma(P + h1 @ Uzr2)
    {
      pH = loadPj(t, 5); // prefetch stage-4 P
      f32x4 a0 = (f32x4){0.f,0.f,0.f,0.f}, a1 = (f32x4){0.f,0.f,0.f,0.f};
      const bf16x8* ab = (const bf16x8*)h1b;
#pragma unroll
      for (int kt = 0; kt < 8; ++kt) {
        bf16x8 A = ab[kt * 64 + lane];
        a0 = mfma16(A, fz[2 * kt], a0);
        a1 = mfma16(A, fz[2 * kt + 1], a1);
        fz[2 * kt]     = pz1[(2 * kt) * 64];     // reload -> next-step stage-1
        fz[2 * kt + 1] = pz1[(2 * kt + 1) * 64];
      }
#pragma unroll
      for (int nt = 0; nt < 2; ++nt) {
        float4 pp = nt ? pC1 : pC0;
        f32x4 ac = nt ? a1 : a0;
        if (w < 8) {
          int col = w * 32 + nt * 16 + lrow;
#pragma unroll
          for (int rr = 0; rr < 4; ++rr)
            zf[lgrp * 4 + rr][col] = 0.875f * sigm_f(ac[rr] + pp[rr]) + 0.125f;
        } else {
          int col = (w - 8) * 32 + nt * 16 + lrow;
          int fo = (col >> 3) * 16, fe = col & 7;
#pragma unroll
          for (int rr = 0; rr < 4; ++rr) {
            int row = lgrp * 4 + rr;
            float r2 = sigm_f(ac[rr] + pp[rr]);
            float h1v = __bfloat162float(h1b[(fo + row) * 8 + fe]);
            agb[(fo + row) * 8 + fe] = __float2bfloat16(r2 * h1v);
          }
        }
      }
    }
    __syncthreads();

    // ================= stage 4: g2 = tanh(P + agb @ Ug2); h2 update
    {
      pA = loadPj(tn, 0); pB = loadPj(tn, 1); // prefetch next-step stage-1 P
      f32x4 a2 = (f32x4){0.f,0.f,0.f,0.f};
      const bf16x8* ab = (const bf16x8*)agb;
#pragma unroll
      for (int kt = 0; kt < 8; ++kt) {
        bf16x8 A = ab[kt * 64 + lane];
        a2 = mfma16(A, fg[kt], a2);
        fg[kt] = pg1[kt * 64]; // reload -> next-step stage-2 frags
      }
      int col = w * 16 + lrow;
      int fo = (col >> 3) * 16, fe = col & 7;
#pragma unroll
      for (int rr = 0; rr < 4; ++rr) {
        int row = lgrp * 4 + rr;
        float gv = tanh_f(a2[rr] + pH[rr]);
        float z  = zf[row][col];
        float zq = floorf(z * Q10) * IQ10;
        float h  = h2f[row][col];
        h = floorf(h * zq * Q23) * IQ23;
        h = h + rintf((1.f - z) * gv * Q23) * IQ23;
        h2f[row][col] = h;
        h2b[(fo + row) * 8 + fe] = __float2bfloat16(h);
        if (LAYER == 0)
          Hseq[((size_t)t * BATCH + b0 + row) * HID + HALF + col] = __float2bfloat16(h);
        if (t == T_STEPS - 1)
          out[(size_t)LAYER * (BATCH * HID) + (b0 + row) * HID + HALF + col] = h;
      }
    }
    __syncthreads();
  }
}

// ---------------------------------------------------------------- launch
extern "C" void kernel_launch(void* const* d_in, const int* in_sizes, int n_in,
                              void* d_out, int out_size, void* d_ws, size_t ws_size,
                              hipStream_t stream) {
  const int*   seq = (const int*)d_in[0];
  const float* emb = (const float*)d_in[1];
  AllW aw;
  // setup order per layer: Wzr1,bzr1,Wg1,bg1,Wzr2,bzr2,Wg2,bg2
  for (int l = 0; l < 2; ++l)
    for (int s = 0; s < 4; ++s) {
      aw.W[l * 4 + s] = (const float*)d_in[2 + l * 8 + s * 2];
      aw.b[l * 4 + s] = (const float*)d_in[2 + l * 8 + s * 2 + 1];
    }

  uint8_t* wp = (uint8_t*)d_ws;
  float* Psw = (float*)wp;                   wp += (size_t)4 * 256 * 6 * 16 * 256 * 4; // 100.7 MB
  __hip_bfloat16* X0 = (__hip_bfloat16*)wp;  wp += (size_t)MROWS * HID * 2;            // 16.8 MB
  __hip_bfloat16* H0 = (__hip_bfloat16*)wp;  wp += (size_t)MROWS * HID * 2;            // 16.8 MB
  __hip_bfloat16* Wsw = (__hip_bfloat16*)wp; wp += (size_t)2 * FRAGS_PER_LAYER * 8 * 2;// 1.6 MB
  __hip_bfloat16* WxT = (__hip_bfloat16*)wp; wp += (size_t)2 * NCOLS * 512 * 2;        // 3.1 MB
  float* biasAll = (float*)wp;               wp += (size_t)2 * NCOLS * 4;

  float* out = (float*)d_out;

  const int prepN = (2 * FRAGS_PER_LAYER + 2 * NCOLS * 64 + 2 * NCOLS + 255) / 256;
  prep_weights<<<prepN, 256, 0, stream>>>(aw, Wsw, WxT, biasAll);
  embed_gather<<<(MROWS * 128) / 256, 256, 0, stream>>>(seq, emb, X0);

  gemm_p<<<dim3(24, 256), 256, 0, stream>>>(X0, WxT, biasAll, Psw);
  rec_kernel<0><<<4, 1024, 0, stream>>>(Wsw, Psw, out, H0);
  gemm_p<<<dim3(24, 256), 256, 0, stream>>>(H0, WxT + (size_t)NCOLS * 512, biasAll + NCOLS, Psw);
  rec_kernel<1><<<4, 1024, 0, stream>>>(Wsw + (size_t)FRAGS_PER_LAYER * 8, Psw, out, nullptr);
}

// Round 3
// 12043.114 us; speedup vs baseline: 1.1692x; 1.1692x over previous
//
#include <hip/hip_runtime.h>
#include <hip/hip_bf16.h>
#include <stdint.h>

#define T_STEPS 256
#define BATCH   64
#define HID     512
#define HALF    256
#define NCOLS   1536              // [zr1:512 | g1:256 | zr2:512 | g2:256]
#define MROWS   (T_STEPS * BATCH) // 16384
#define SLICE_N 100
#define SAVED_OFF (2 * BATCH * HID) // 65536 floats into d_out

// swizzled weight stream: per layer, 49152 fragments of 16B:
//   stage0 zr1: frags [0,16384)        (w:16, idx:16, lane:64)
//   stage1 g1 : frags [16384,24576)    (w:16, idx:8,  lane:64)
//   stage2 zr2: frags [24576,40960)
//   stage3 g2 : frags [40960,49152)
#define SB0 0
#define SB1 16384
#define SB2 24576
#define SB3 40960
#define FRAGS_PER_LAYER 49152

typedef short bf16x8 __attribute__((ext_vector_type(8)));
typedef float f32x4  __attribute__((ext_vector_type(4)));

__device__ __forceinline__ f32x4 mfma16(bf16x8 a, bf16x8 b, f32x4 c) {
  return __builtin_amdgcn_mfma_f32_16x16x32_bf16(a, b, c, 0, 0, 0);
}
__device__ __forceinline__ float sigm_f(float x) {
  return 1.f / (1.f + __expf(-x));
}
__device__ __forceinline__ float tanh_f(float x) {
  x = fminf(fmaxf(x, -30.f), 30.f);
  float e = __expf(-2.f * x);
  return (1.f - e) / (1.f + e);
}

struct AllW {
  const float* W[8]; // l0: zr1,g1,zr2,g2 ; l1: zr1,g1,zr2,g2
  const float* b[8];
};

// ---------------------------------------------------------------- prep
__global__ void prep_weights(AllW aw, __hip_bfloat16* __restrict__ Wsw,
                             __hip_bfloat16* __restrict__ WxT,
                             float* __restrict__ biasAll) {
  int tid = blockIdx.x * blockDim.x + threadIdx.x;
  const int NW = 2 * FRAGS_PER_LAYER;          // 98304 fragment threads
  const int NX = 2 * NCOLS * 64;               // 196608 WxT threads (8 elems each)
  if (tid < NW) {
    int l = tid / FRAGS_PER_LAYER, r = tid % FRAGS_PER_LAYER;
    int s, fi;
    if (r < SB1)      { s = 0; fi = r; }
    else if (r < SB2) { s = 1; fi = r - SB1; }
    else if (r < SB3) { s = 2; fi = r - SB2; }
    else              { s = 3; fi = r - SB3; }
    int lane = fi & 63, lrow = lane & 15, lgrp = lane >> 4;
    int zr = (s == 0 || s == 2);
    int w   = zr ? (fi >> 10) : (fi >> 9);
    int idx = zr ? ((fi >> 6) & 15) : ((fi >> 6) & 7);
    int col, kt;
    if (zr) { kt = idx >> 1; col = w * 32 + (idx & 1) * 16 + lrow; }
    else    { kt = idx;      col = w * 16 + lrow; }
    const float* W = aw.W[l * 4 + s];
    int nc = zr ? 512 : 256;
    int kbase = 512 + kt * 32 + lgrp * 8;
    __hip_bfloat16 frag[8];
#pragma unroll
    for (int e = 0; e < 8; ++e)
      frag[e] = __float2bfloat16(W[(size_t)(kbase + e) * nc + col]);
    *(uint4*)&Wsw[(size_t)tid * 8] = *(uint4*)frag;
  } else if (tid < NW + NX) {
    int u = tid - NW;
    int l = u / (NCOLS * 64), r = u % (NCOLS * 64);
    int c = r >> 6, k0 = (r & 63) * 8;
    const float* W; int nc, cc;
    if (c < 512)       { W = aw.W[l*4+0]; nc = 512; cc = c;        }
    else if (c < 768)  { W = aw.W[l*4+1]; nc = 256; cc = c - 512;  }
    else if (c < 1280) { W = aw.W[l*4+2]; nc = 512; cc = c - 768;  }
    else               { W = aw.W[l*4+3]; nc = 256; cc = c - 1280; }
    __hip_bfloat16 frag[8];
#pragma unroll
    for (int e = 0; e < 8; ++e)
      frag[e] = __float2bfloat16(W[(size_t)(k0 + e) * nc + cc]);
    *(uint4*)&WxT[((size_t)l * NCOLS + c) * 512 + k0] = *(uint4*)frag;
  } else if (tid < NW + NX + 2 * NCOLS) {
    int c = tid - NW - NX;
    int l = c / NCOLS, cc = c % NCOLS;
    const float* b; int off;
    if (cc < 512)       { b = aw.b[l*4+0]; off = cc;        }
    else if (cc < 768)  { b = aw.b[l*4+1]; off = cc - 512;  }
    else if (cc < 1280) { b = aw.b[l*4+2]; off = cc - 768;  }
    else                { b = aw.b[l*4+3]; off = cc - 1280; }
    biasAll[c] = b[off];
  }
}

// ---------------------------------------------------------------- embed gather
__global__ void embed_gather(const int* __restrict__ seq, const float* __restrict__ emb,
                             __hip_bfloat16* __restrict__ X0) {
  int i = blockIdx.x * blockDim.x + threadIdx.x; // over 16384*128
  int row = i >> 7, c4 = (i & 127) * 4;
  int idx = seq[row];
  float4 v = *(const float4*)&emb[(size_t)idx * HID + c4];
  union { __hip_bfloat16 h[4]; uint2 u; } pk;
  pk.h[0] = __float2bfloat16(v.x);
  pk.h[1] = __float2bfloat16(v.y);
  pk.h[2] = __float2bfloat16(v.z);
  pk.h[3] = __float2bfloat16(v.w);
  *(uint2*)&X0[(size_t)row * HID + c4] = pk.u;
}

// ---------------------------------------------------------------- P_sw = A @ WxT^T + bias
// P_sw[g:4][t:256][jg:6][w:16][lane:64][rr:4] f32 where
//   jg0/1 = zr1 nt0/1, jg2 = g1, jg3/4 = zr2 nt0/1, jg5 = g2.
__global__ __launch_bounds__(256) void gemm_p(const __hip_bfloat16* __restrict__ A,
                                              const __hip_bfloat16* __restrict__ WT,
                                              const float* __restrict__ bias,
                                              float* __restrict__ Psw) {
  const int tid = threadIdx.x;
  const int lane = tid & 63, w = tid >> 6;
  const int lrow = lane & 15, lgrp = lane >> 4;
  const int n0 = blockIdx.x * 64, m0 = blockIdx.y * 64;
  const int wm = w & 1, wn = w >> 1;
  __shared__ __hip_bfloat16 As[64][72];
  f32x4 acc[2][2];
#pragma unroll
  for (int a = 0; a < 2; ++a)
#pragma unroll
    for (int b = 0; b < 2; ++b) acc[a][b] = (f32x4){0.f, 0.f, 0.f, 0.f};

  const int lr = tid >> 2, lc = (tid & 3) * 16;
  for (int k0 = 0; k0 < 512; k0 += 64) {
    *(uint4*)&As[lr][lc]     = *(const uint4*)&A[((size_t)m0 + lr) * 512 + k0 + lc];
    *(uint4*)&As[lr][lc + 8] = *(const uint4*)&A[((size_t)m0 + lr) * 512 + k0 + lc + 8];
    __syncthreads();
#pragma unroll
    for (int kt = 0; kt < 2; ++kt) {
      bf16x8 a0 = *(const bf16x8*)&As[wm * 32 + lrow][kt * 32 + lgrp * 8];
      bf16x8 a1 = *(const bf16x8*)&As[wm * 32 + 16 + lrow][kt * 32 + lgrp * 8];
      bf16x8 b0 = *(const bf16x8*)&WT[((size_t)n0 + wn * 32 + lrow) * 512 + k0 + kt * 32 + lgrp * 8];
      bf16x8 b1 = *(const bf16x8*)&WT[((size_t)n0 + wn * 32 + 16 + lrow) * 512 + k0 + kt * 32 + lgrp * 8];
      acc[0][0] = mfma16(a0, b0, acc[0][0]);
      acc[0][1] = mfma16(a0, b1, acc[0][1]);
      acc[1][0] = mfma16(a1, b0, acc[1][0]);
      acc[1][1] = mfma16(a1, b1, acc[1][1]);
    }
    __syncthreads();
  }
  const int t = m0 >> 6;
#pragma unroll
  for (int mt = 0; mt < 2; ++mt) {
    int g = wm * 2 + mt;
#pragma unroll
    for (int nt = 0; nt < 2; ++nt) {
      int colb = n0 + wn * 32 + nt * 16; // wave-uniform
      int jg, wr;
      if (colb < 512)       { jg = (colb >> 4) & 1; wr = colb >> 5; }
      else if (colb < 768)  { jg = 2; wr = (colb - 512) >> 4; }
      else if (colb < 1280) { int c2 = colb - 768; jg = 3 + ((c2 >> 4) & 1); wr = c2 >> 5; }
      else                  { jg = 5; wr = (colb - 1280) >> 4; }
      float bv = bias[colb + lrow];
      float4 v;
      v.x = acc[mt][nt][0] + bv;
      v.y = acc[mt][nt][1] + bv;
      v.z = acc[mt][nt][2] + bv;
      v.w = acc[mt][nt][3] + bv;
      size_t off = ((((size_t)g * 256 + t) * 6 + jg) * 16 + wr) * 256 + (size_t)lane * 4;
      *(float4*)&Psw[off] = v;
    }
  }
}

// ---------------------------------------------------------------- recurrence
// 4 WGs x 16 batch rows x 16 waves. Rolling 16-slot register fragment buffer;
// __launch_bounds__(1024,4) -> 128-VGPR budget (NOT the default 8-waves/EU
// 64-VGPR budget that spilled everything in R1/R2).
template <int LAYER>
__global__ __launch_bounds__(1024, 4) void rec_kernel(
    const __hip_bfloat16* __restrict__ WswL,
    const float* __restrict__ PswAll,
    float* __restrict__ out,
    __hip_bfloat16* __restrict__ Hseq) {
  const int tid = threadIdx.x;
  const int lane = tid & 63, w = tid >> 6;
  const int lrow = lane & 15, lgrp = lane >> 4;
  const int g4 = blockIdx.x;
  const int b0 = g4 * 16;

  // master f32 state + z staging (stride 258: lgrp bank offset 8 -> 2-way, free)
  __shared__ float h1f[16][258], h2f[16][258], zf[16][258];
  // bf16 A-operand buffers, fragment-major: elem(row,k) at ((k>>3)*16+row)*8+(k&7)
  __shared__ __hip_bfloat16 h1b[4096], h2b[4096], agb[4096];

  {
    __hip_bfloat16 z0 = __float2bfloat16(0.f);
    for (int i = tid; i < 4096; i += 1024) { h1b[i] = z0; h2b[i] = z0; }
    float* f1 = &h1f[0][0]; float* f2 = &h2f[0][0];
    for (int i = tid; i < 16 * 258; i += 1024) { f1[i] = 0.f; f2[i] = 0.f; }
    if (LAYER == 1) {
      for (int i = tid; i < 16 * SLICE_N; i += 1024)
        out[SAVED_OFF + (size_t)(b0 + i / SLICE_N) * SLICE_N + (i % SLICE_N)] = 0.f;
    }
  }

  const bf16x8* Wf = (const bf16x8*)WswL;
  const bf16x8* pz1 = Wf + SB0 + (size_t)w * 16 * 64 + lane;
  const bf16x8* pg1 = Wf + SB1 + (size_t)w * 8 * 64 + lane;
  const bf16x8* pz2 = Wf + SB2 + (size_t)w * 16 * 64 + lane;
  const bf16x8* pg2 = Wf + SB3 + (size_t)w * 8 * 64 + lane;

  const float* Psw = PswAll + (size_t)g4 * 256 * 6 * 16 * 256;
  auto loadPj = [&](int t, int jg) -> float4 {
    return *(const float4*)&Psw[(((size_t)t * 6 + jg) * 16 + w) * 256 + (size_t)lane * 4];
  };

  // rolling fragment buffer: fr[i] holds "idx i" of whichever stage is next.
  bf16x8 fr[16];
#pragma unroll
  for (int i = 0; i < 16; ++i) fr[i] = pz1[i * 64];
  float4 pA = loadPj(0, 0), pB = loadPj(0, 1);
  float4 pG, pC0, pC1, pH;
  __syncthreads();

  const float Q23 = 8388608.f, IQ23 = 1.f / 8388608.f;
  const float Q10 = 1024.f,    IQ10 = 1.f / 1024.f;

  for (int t = 0; t < T_STEPS; ++t) {
    const int tn = (t + 1 < T_STEPS) ? (t + 1) : (T_STEPS - 1);
    // ================= stage 1: zr1 = sigma(P + h2 @ Uzr1); load g1 -> fr[0..7]
    {
      pG = loadPj(t, 2);
      f32x4 a0 = (f32x4){0.f,0.f,0.f,0.f}, a1 = (f32x4){0.f,0.f,0.f,0.f};
      const bf16x8* ab = (const bf16x8*)h2b;
#pragma unroll
      for (int kt = 0; kt < 8; ++kt) {
        bf16x8 A = ab[kt * 64 + lane];
        a0 = mfma16(A, fr[2 * kt], a0);
        a1 = mfma16(A, fr[2 * kt + 1], a1);
        if (kt < 4) {
          fr[2 * kt]     = pg1[(2 * kt) * 64];
          fr[2 * kt + 1] = pg1[(2 * kt + 1) * 64];
        }
      }
#pragma unroll
      for (int nt = 0; nt < 2; ++nt) {
        float4 pp = nt ? pB : pA;
        f32x4 ac = nt ? a1 : a0;
        if (w < 8) {
          int col = w * 32 + nt * 16 + lrow;
#pragma unroll
          for (int rr = 0; rr < 4; ++rr)
            zf[lgrp * 4 + rr][col] = 0.875f * sigm_f(ac[rr] + pp[rr]) + 0.125f;
        } else {
          int col = (w - 8) * 32 + nt * 16 + lrow;
          int fo = (col >> 3) * 16, fe = col & 7;
#pragma unroll
          for (int rr = 0; rr < 4; ++rr) {
            int row = lgrp * 4 + rr;
            float r1 = sigm_f(ac[rr] + pp[rr]);
            float h2v = __bfloat162float(h2b[(fo + row) * 8 + fe]);
            agb[(fo + row) * 8 + fe] = __float2bfloat16(r1 * h2v);
          }
        }
      }
    }
    __syncthreads();

    // ================= stage 2: g1 = tanh(P + agb @ Ug1); h1 update; load zr2 -> fr[0..15]
    {
      pC0 = loadPj(t, 3); pC1 = loadPj(t, 4);
      f32x4 a2 = (f32x4){0.f,0.f,0.f,0.f};
      const bf16x8* ab = (const bf16x8*)agb;
#pragma unroll
      for (int kt = 0; kt < 8; ++kt) {
        bf16x8 A = ab[kt * 64 + lane];
        a2 = mfma16(A, fr[kt], a2);
        fr[kt]     = pz2[kt * 64];
        fr[8 + kt] = pz2[(8 + kt) * 64];
      }
      int col = w * 16 + lrow;
      int fo = (col >> 3) * 16, fe = col & 7;
#pragma unroll
      for (int rr = 0; rr < 4; ++rr) {
        int row = lgrp * 4 + rr;
        float gv = tanh_f(a2[rr] + pG[rr]);
        float z  = zf[row][col];
        float zq = floorf(z * Q10) * IQ10;
        float h  = h1f[row][col];
        h = floorf(h * zq * Q23) * IQ23;
        h = h + rintf((1.f - z) * gv * Q23) * IQ23;
        h1f[row][col] = h;
        h1b[(fo + row) * 8 + fe] = __float2bfloat16(h);
        if (LAYER == 0)
          Hseq[((size_t)t * BATCH + b0 + row) * HID + col] = __float2bfloat16(h);
        if (LAYER == 1 && col < SLICE_N)
          out[SAVED_OFF + (size_t)(t + 1) * (BATCH * SLICE_N) + (b0 + row) * SLICE_N + col] = h;
        if (t == T_STEPS - 1)
          out[(size_t)LAYER * (BATCH * HID) + (b0 + row) * HID + col] = h;
      }
    }
    __syncthreads();

    // ================= stage 3: zr2 = sigma(P + h1 @ Uzr2); load g2 -> fr[0..7]
    {
      pH = loadPj(t, 5);
      f32x4 a0 = (f32x4){0.f,0.f,0.f,0.f}, a1 = (f32x4){0.f,0.f,0.f,0.f};
      const bf16x8* ab = (const bf16x8*)h1b;
#pragma unroll
      for (int kt = 0; kt < 8; ++kt) {
        bf16x8 A = ab[kt * 64 + lane];
        a0 = mfma16(A, fr[2 * kt], a0);
        a1 = mfma16(A, fr[2 * kt + 1], a1);
        if (kt < 4) {
          fr[2 * kt]     = pg2[(2 * kt) * 64];
          fr[2 * kt + 1] = pg2[(2 * kt + 1) * 64];
        }
      }
#pragma unroll
      for (int nt = 0; nt < 2; ++nt) {
        float4 pp = nt ? pC1 : pC0;
        f32x4 ac = nt ? a1 : a0;
        if (w < 8) {
          int col = w * 32 + nt * 16 + lrow;
#pragma unroll
          for (int rr = 0; rr < 4; ++rr)
            zf[lgrp * 4 + rr][col] = 0.875f * sigm_f(ac[rr] + pp[rr]) + 0.125f;
        } else {
          int col = (w - 8) * 32 + nt * 16 + lrow;
          int fo = (col >> 3) * 16, fe = col & 7;
#pragma unroll
          for (int rr = 0; rr < 4; ++rr) {
            int row = lgrp * 4 + rr;
            float r2 = sigm_f(ac[rr] + pp[rr]);
            float h1v = __bfloat162float(h1b[(fo + row) * 8 + fe]);
            agb[(fo + row) * 8 + fe] = __float2bfloat16(r2 * h1v);
          }
        }
      }
    }
    __syncthreads();

    // ================= stage 4: g2 = tanh(P + agb @ Ug2); h2 update; load zr1(t+1) -> fr
    {
      pA = loadPj(tn, 0); pB = loadPj(tn, 1);
      f32x4 a2 = (f32x4){0.f,0.f,0.f,0.f};
      const bf16x8* ab = (const bf16x8*)agb;
#pragma unroll
      for (int kt = 0; kt < 8; ++kt) {
        bf16x8 A = ab[kt * 64 + lane];
        a2 = mfma16(A, fr[kt], a2);
        fr[kt]     = pz1[kt * 64];
        fr[8 + kt] = pz1[(8 + kt) * 64];
      }
      int col = w * 16 + lrow;
      int fo = (col >> 3) * 16, fe = col & 7;
#pragma unroll
      for (int rr = 0; rr < 4; ++rr) {
        int row = lgrp * 4 + rr;
        float gv = tanh_f(a2[rr] + pH[rr]);
        float z  = zf[row][col];
        float zq = floorf(z * Q10) * IQ10;
        float h  = h2f[row][col];
        h = floorf(h * zq * Q23) * IQ23;
        h = h + rintf((1.f - z) * gv * Q23) * IQ23;
        h2f[row][col] = h;
        h2b[(fo + row) * 8 + fe] = __float2bfloat16(h);
        if (LAYER == 0)
          Hseq[((size_t)t * BATCH + b0 + row) * HID + HALF + col] = __float2bfloat16(h);
        if (t == T_STEPS - 1)
          out[(size_t)LAYER * (BATCH * HID) + (b0 + row) * HID + HALF + col] = h;
      }
    }
    __syncthreads();
  }
}

// ---------------------------------------------------------------- launch
extern "C" void kernel_launch(void* const* d_in, const int* in_sizes, int n_in,
                              void* d_out, int out_size, void* d_ws, size_t ws_size,
                              hipStream_t stream) {
  const int*   seq = (const int*)d_in[0];
  const float* emb = (const float*)d_in[1];
  AllW aw;
  for (int l = 0; l < 2; ++l)
    for (int s = 0; s < 4; ++s) {
      aw.W[l * 4 + s] = (const float*)d_in[2 + l * 8 + s * 2];
      aw.b[l * 4 + s] = (const float*)d_in[2 + l * 8 + s * 2 + 1];
    }

  uint8_t* wp = (uint8_t*)d_ws;
  float* Psw = (float*)wp;                   wp += (size_t)4 * 256 * 6 * 16 * 256 * 4; // 100.7 MB
  __hip_bfloat16* X0 = (__hip_bfloat16*)wp;  wp += (size_t)MROWS * HID * 2;            // 16.8 MB
  __hip_bfloat16* H0 = (__hip_bfloat16*)wp;  wp += (size_t)MROWS * HID * 2;            // 16.8 MB
  __hip_bfloat16* Wsw = (__hip_bfloat16*)wp; wp += (size_t)2 * FRAGS_PER_LAYER * 8 * 2;// 1.6 MB
  __hip_bfloat16* WxT = (__hip_bfloat16*)wp; wp += (size_t)2 * NCOLS * 512 * 2;        // 3.1 MB
  float* biasAll = (float*)wp;               wp += (size_t)2 * NCOLS * 4;

  float* out = (float*)d_out;

  const int prepN = (2 * FRAGS_PER_LAYER + 2 * NCOLS * 64 + 2 * NCOLS + 255) / 256;
  prep_weights<<<prepN, 256, 0, stream>>>(aw, Wsw, WxT, biasAll);
  embed_gather<<<(MROWS * 128) / 256, 256, 0, stream>>>(seq, emb, X0);

  gemm_p<<<dim3(24, 256), 256, 0, stream>>>(X0, WxT, biasAll, Psw);
  rec_kernel<0><<<4, 1024, 0, stream>>>(Wsw, Psw, out, H0);
  gemm_p<<<dim3(24, 256), 256, 0, stream>>>(H0, WxT + (size_t)NCOLS * 512, biasAll + NCOLS, Psw);
  rec_kernel<1><<<4, 1024, 0, stream>>>(Wsw + (size_t)FRAGS_PER_LAYER * 8, Psw, out, nullptr);
}

// Round 4
// 11569.268 us; speedup vs baseline: 1.2171x; 1.0410x over previous
//
#include <hip/hip_runtime.h>
#include <hip/hip_bf16.h>
#include <stdint.h>

#define T_STEPS 256
#define BATCH   64
#define HID     512
#define HALF    256
#define NCOLS   1536              // [zr1:512 | g1:256 | zr2:512 | g2:256]
#define MROWS   (T_STEPS * BATCH) // 16384
#define SLICE_N 100
#define SAVED_OFF (2 * BATCH * HID) // 65536 floats into d_out

// swizzled weight stream: per layer, 49152 fragments of 16B:
//   stage0 zr1: frags [0,16384)        (w:16, idx:16, lane:64)
//   stage1 g1 : frags [16384,24576)    (w:16, idx:8,  lane:64)
//   stage2 zr2: frags [24576,40960)
//   stage3 g2 : frags [40960,49152)
#define SB0 0
#define SB1 16384
#define SB2 24576
#define SB3 40960
#define FRAGS_PER_LAYER 49152

typedef short bf16x8 __attribute__((ext_vector_type(8)));
typedef float f32x4  __attribute__((ext_vector_type(4)));

__device__ __forceinline__ f32x4 mfma16(bf16x8 a, bf16x8 b, f32x4 c) {
  return __builtin_amdgcn_mfma_f32_16x16x32_bf16(a, b, c, 0, 0, 0);
}
__device__ __forceinline__ float sigm_f(float x) {
  return __builtin_amdgcn_rcpf(1.f + __expf(-x));
}
__device__ __forceinline__ float tanh_f(float x) {
  x = fminf(fmaxf(x, -30.f), 30.f);
  float e = __expf(-2.f * x);
  return (1.f - e) * __builtin_amdgcn_rcpf(1.f + e);
}

struct AllW {
  const float* W[8]; // l0: zr1,g1,zr2,g2 ; l1: zr1,g1,zr2,g2
  const float* b[8];
};

// ---------------------------------------------------------------- prep
__global__ void prep_weights(AllW aw, __hip_bfloat16* __restrict__ Wsw,
                             __hip_bfloat16* __restrict__ WxT,
                             float* __restrict__ biasAll) {
  int tid = blockIdx.x * blockDim.x + threadIdx.x;
  const int NW = 2 * FRAGS_PER_LAYER;          // 98304 fragment threads
  const int NX = 2 * NCOLS * 64;               // 196608 WxT threads (8 elems each)
  if (tid < NW) {
    int l = tid / FRAGS_PER_LAYER, r = tid % FRAGS_PER_LAYER;
    int s, fi;
    if (r < SB1)      { s = 0; fi = r; }
    else if (r < SB2) { s = 1; fi = r - SB1; }
    else if (r < SB3) { s = 2; fi = r - SB2; }
    else              { s = 3; fi = r - SB3; }
    int lane = fi & 63, lrow = lane & 15, lgrp = lane >> 4;
    int zr = (s == 0 || s == 2);
    int w   = zr ? (fi >> 10) : (fi >> 9);
    int idx = zr ? ((fi >> 6) & 15) : ((fi >> 6) & 7);
    int col, kt;
    if (zr) { kt = idx >> 1; col = w * 32 + (idx & 1) * 16 + lrow; }
    else    { kt = idx;      col = w * 16 + lrow; }
    const float* W = aw.W[l * 4 + s];
    int nc = zr ? 512 : 256;
    int kbase = 512 + kt * 32 + lgrp * 8;
    __hip_bfloat16 frag[8];
#pragma unroll
    for (int e = 0; e < 8; ++e)
      frag[e] = __float2bfloat16(W[(size_t)(kbase + e) * nc + col]);
    *(uint4*)&Wsw[(size_t)tid * 8] = *(uint4*)frag;
  } else if (tid < NW + NX) {
    int u = tid - NW;
    int l = u / (NCOLS * 64), r = u % (NCOLS * 64);
    int c = r >> 6, k0 = (r & 63) * 8;
    const float* W; int nc, cc;
    if (c < 512)       { W = aw.W[l*4+0]; nc = 512; cc = c;        }
    else if (c < 768)  { W = aw.W[l*4+1]; nc = 256; cc = c - 512;  }
    else if (c < 1280) { W = aw.W[l*4+2]; nc = 512; cc = c - 768;  }
    else               { W = aw.W[l*4+3]; nc = 256; cc = c - 1280; }
    __hip_bfloat16 frag[8];
#pragma unroll
    for (int e = 0; e < 8; ++e)
      frag[e] = __float2bfloat16(W[(size_t)(k0 + e) * nc + cc]);
    *(uint4*)&WxT[((size_t)l * NCOLS + c) * 512 + k0] = *(uint4*)frag;
  } else if (tid < NW + NX + 2 * NCOLS) {
    int c = tid - NW - NX;
    int l = c / NCOLS, cc = c % NCOLS;
    const float* b; int off;
    if (cc < 512)       { b = aw.b[l*4+0]; off = cc;        }
    else if (cc < 768)  { b = aw.b[l*4+1]; off = cc - 512;  }
    else if (cc < 1280) { b = aw.b[l*4+2]; off = cc - 768;  }
    else                { b = aw.b[l*4+3]; off = cc - 1280; }
    biasAll[c] = b[off];
  }
}

// ---------------------------------------------------------------- embed gather
__global__ void embed_gather(const int* __restrict__ seq, const float* __restrict__ emb,
                             __hip_bfloat16* __restrict__ X0) {
  int i = blockIdx.x * blockDim.x + threadIdx.x; // over 16384*128
  int row = i >> 7, c4 = (i & 127) * 4;
  int idx = seq[row];
  float4 v = *(const float4*)&emb[(size_t)idx * HID + c4];
  union { __hip_bfloat16 h[4]; uint2 u; } pk;
  pk.h[0] = __float2bfloat16(v.x);
  pk.h[1] = __float2bfloat16(v.y);
  pk.h[2] = __float2bfloat16(v.z);
  pk.h[3] = __float2bfloat16(v.w);
  *(uint2*)&X0[(size_t)row * HID + c4] = pk.u;
}

// ---------------------------------------------------------------- P_sw = A @ WxT^T + bias
// P_sw[g:4][t:256][jg:6][w:16][lane:64][rr:4] f32 where
//   jg0/1 = zr1 nt0/1, jg2 = g1, jg3/4 = zr2 nt0/1, jg5 = g2.
__global__ __launch_bounds__(256) void gemm_p(const __hip_bfloat16* __restrict__ A,
                                              const __hip_bfloat16* __restrict__ WT,
                                              const float* __restrict__ bias,
                                              float* __restrict__ Psw) {
  const int tid = threadIdx.x;
  const int lane = tid & 63, w = tid >> 6;
  const int lrow = lane & 15, lgrp = lane >> 4;
  const int n0 = blockIdx.x * 64, m0 = blockIdx.y * 64;
  const int wm = w & 1, wn = w >> 1;
  __shared__ __hip_bfloat16 As[64][72];
  f32x4 acc[2][2];
#pragma unroll
  for (int a = 0; a < 2; ++a)
#pragma unroll
    for (int b = 0; b < 2; ++b) acc[a][b] = (f32x4){0.f, 0.f, 0.f, 0.f};

  const int lr = tid >> 2, lc = (tid & 3) * 16;
  for (int k0 = 0; k0 < 512; k0 += 64) {
    *(uint4*)&As[lr][lc]     = *(const uint4*)&A[((size_t)m0 + lr) * 512 + k0 + lc];
    *(uint4*)&As[lr][lc + 8] = *(const uint4*)&A[((size_t)m0 + lr) * 512 + k0 + lc + 8];
    __syncthreads();
#pragma unroll
    for (int kt = 0; kt < 2; ++kt) {
      bf16x8 a0 = *(const bf16x8*)&As[wm * 32 + lrow][kt * 32 + lgrp * 8];
      bf16x8 a1 = *(const bf16x8*)&As[wm * 32 + 16 + lrow][kt * 32 + lgrp * 8];
      bf16x8 b0 = *(const bf16x8*)&WT[((size_t)n0 + wn * 32 + lrow) * 512 + k0 + kt * 32 + lgrp * 8];
      bf16x8 b1 = *(const bf16x8*)&WT[((size_t)n0 + wn * 32 + 16 + lrow) * 512 + k0 + kt * 32 + lgrp * 8];
      acc[0][0] = mfma16(a0, b0, acc[0][0]);
      acc[0][1] = mfma16(a0, b1, acc[0][1]);
      acc[1][0] = mfma16(a1, b0, acc[1][0]);
      acc[1][1] = mfma16(a1, b1, acc[1][1]);
    }
    __syncthreads();
  }
  const int t = m0 >> 6;
#pragma unroll
  for (int mt = 0; mt < 2; ++mt) {
    int g = wm * 2 + mt;
#pragma unroll
    for (int nt = 0; nt < 2; ++nt) {
      int colb = n0 + wn * 32 + nt * 16; // wave-uniform
      int jg, wr;
      if (colb < 512)       { jg = (colb >> 4) & 1; wr = colb >> 5; }
      else if (colb < 768)  { jg = 2; wr = (colb - 512) >> 4; }
      else if (colb < 1280) { int c2 = colb - 768; jg = 3 + ((c2 >> 4) & 1); wr = c2 >> 5; }
      else                  { jg = 5; wr = (colb - 1280) >> 4; }
      float bv = bias[colb + lrow];
      float4 v;
      v.x = acc[mt][nt][0] + bv;
      v.y = acc[mt][nt][1] + bv;
      v.z = acc[mt][nt][2] + bv;
      v.w = acc[mt][nt][3] + bv;
      size_t off = ((((size_t)g * 256 + t) * 6 + jg) * 16 + wr) * 256 + (size_t)lane * 4;
      *(float4*)&Psw[off] = v;
    }
  }
}

// ---------------------------------------------------------------- recurrence
// 4 WGs x 16 batch rows x 16 waves. Rolling 16-slot register fragment buffer.
// Real occupancy is grid-limited to 16 waves/CU = 4 waves/EU, so granting the
// compiler a 256-VGPR budget via amdgpu_waves_per_eu(2,4) costs nothing.
// (__launch_bounds__(1024,4) empirically did NOT lift the 64-VGPR cap.)
template <int LAYER>
__global__ __attribute__((amdgpu_waves_per_eu(2, 4))) __launch_bounds__(1024)
void rec_kernel(
    const __hip_bfloat16* __restrict__ WswL,
    const float* __restrict__ PswAll,
    float* __restrict__ out,
    __hip_bfloat16* __restrict__ Hseq) {
  const int tid = threadIdx.x;
  const int lane = tid & 63, w = tid >> 6;
  const int lrow = lane & 15, lgrp = lane >> 4;
  const int g4 = blockIdx.x;
  const int b0 = g4 * 16;

  // z staging (stride 258: row-to-row bank offset 2 -> conflict-light)
  __shared__ float zf[16][258];
  // bf16 A-operand buffers, fragment-major: elem(row,k) at ((k>>3)*16+row)*8+(k&7)
  __shared__ __hip_bfloat16 h1b[4096], h2b[4096], agb[4096];

  {
    __hip_bfloat16 z0 = __float2bfloat16(0.f);
    for (int i = tid; i < 4096; i += 1024) { h1b[i] = z0; h2b[i] = z0; }
    if (LAYER == 1) {
      for (int i = tid; i < 16 * SLICE_N; i += 1024)
        out[SAVED_OFF + (size_t)(b0 + i / SLICE_N) * SLICE_N + (i % SLICE_N)] = 0.f;
    }
  }

  const bf16x8* Wf = (const bf16x8*)WswL;
  const bf16x8* pz1 = Wf + SB0 + (size_t)w * 16 * 64 + lane;
  const bf16x8* pg1 = Wf + SB1 + (size_t)w * 8 * 64 + lane;
  const bf16x8* pz2 = Wf + SB2 + (size_t)w * 16 * 64 + lane;
  const bf16x8* pg2 = Wf + SB3 + (size_t)w * 8 * 64 + lane;

  // P pointer for this thread; advance by PSTEP floats each time step
  const int PSTEP = 6 * 16 * 256;
  const float* Pp = PswAll + (size_t)g4 * 256 * PSTEP + (size_t)w * 256 + (size_t)lane * 4;
  auto loadPj = [&](int jg) -> float4 {
    return *(const float4*)&Pp[(size_t)jg * 16 * 256];
  };

  // master h state in registers: thread (w,lane) owns rows lgrp*4+rr, col w*16+lrow
  float hreg1[4] = {0.f, 0.f, 0.f, 0.f};
  float hreg2[4] = {0.f, 0.f, 0.f, 0.f};

  // rolling fragment buffer: fr[i] holds "idx i" of whichever stage is next.
  bf16x8 fr[16];
#pragma unroll
  for (int i = 0; i < 16; ++i) fr[i] = pz1[i * 64];
  float4 pA = loadPj(0), pB = loadPj(1);
  float4 pG, pC0, pC1, pH;
  __syncthreads();

  const float Q23 = 8388608.f, IQ23 = 1.f / 8388608.f;
  const float Q10 = 1024.f,    IQ10 = 1.f / 1024.f;

  // loop-invariant indices
  const int colg = w * 16 + lrow;                 // g-stage column
  const int fog = (colg >> 3) * 16, feg = colg & 7;
  __hip_bfloat16* HseqP = (LAYER == 0)
      ? Hseq + ((size_t)b0 + lgrp * 4) * HID + colg : nullptr;
  float* savedP = (LAYER == 1 && colg < SLICE_N)
      ? out + SAVED_OFF + (size_t)BATCH * SLICE_N + (size_t)(b0 + lgrp * 4) * SLICE_N + colg
      : nullptr;

  for (int t = 0; t < T_STEPS; ++t) {
    // ================= stage 1: zr1 = sigma(P + h2 @ Uzr1); load g1 -> fr[0..7]
    {
      pG = loadPj(2);
      f32x4 a0 = (f32x4){0.f,0.f,0.f,0.f}, a1 = (f32x4){0.f,0.f,0.f,0.f};
      const bf16x8* ab = (const bf16x8*)h2b;
#pragma unroll
      for (int kt = 0; kt < 8; ++kt) {
        bf16x8 A = ab[kt * 64 + lane];
        a0 = mfma16(A, fr[2 * kt], a0);
        a1 = mfma16(A, fr[2 * kt + 1], a1);
        if (kt < 4) {
          fr[2 * kt]     = pg1[(2 * kt) * 64];
          fr[2 * kt + 1] = pg1[(2 * kt + 1) * 64];
        }
      }
#pragma unroll
      for (int nt = 0; nt < 2; ++nt) {
        float4 pp = nt ? pB : pA;
        f32x4 ac = nt ? a1 : a0;
        if (w < 8) {
          int col = w * 32 + nt * 16 + lrow;
#pragma unroll
          for (int rr = 0; rr < 4; ++rr)
            zf[lgrp * 4 + rr][col] = 0.875f * sigm_f(ac[rr] + pp[rr]) + 0.125f;
        } else {
          int col = (w - 8) * 32 + nt * 16 + lrow;
          int fo = (col >> 3) * 16, fe = col & 7;
#pragma unroll
          for (int rr = 0; rr < 4; ++rr) {
            int row = lgrp * 4 + rr;
            float r1 = sigm_f(ac[rr] + pp[rr]);
            float h2v = __bfloat162float(h2b[(fo + row) * 8 + fe]);
            agb[(fo + row) * 8 + fe] = __float2bfloat16(r1 * h2v);
          }
        }
      }
    }
    __syncthreads();

    // ================= stage 2: g1 = tanh(P + agb @ Ug1); h1 update; load zr2 -> fr[0..15]
    {
      pC0 = loadPj(3); pC1 = loadPj(4);
      f32x4 a2 = (f32x4){0.f,0.f,0.f,0.f};
      const bf16x8* ab = (const bf16x8*)agb;
#pragma unroll
      for (int kt = 0; kt < 8; ++kt) {
        bf16x8 A = ab[kt * 64 + lane];
        a2 = mfma16(A, fr[kt], a2);
        fr[kt]     = pz2[kt * 64];
        fr[8 + kt] = pz2[(8 + kt) * 64];
      }
#pragma unroll
      for (int rr = 0; rr < 4; ++rr) {
        int row = lgrp * 4 + rr;
        float gv = tanh_f(a2[rr] + pG[rr]);
        float z  = zf[row][colg];
        float zq = floorf(z * Q10) * IQ10;
        float h  = hreg1[rr];
        h = floorf(h * zq * Q23) * IQ23;
        h = h + rintf((1.f - z) * gv * Q23) * IQ23;
        hreg1[rr] = h;
        h1b[(fog + row) * 8 + feg] = __float2bfloat16(h);
        if (LAYER == 0)
          HseqP[(size_t)rr * HID] = __float2bfloat16(h);
        if (LAYER == 1 && savedP)
          savedP[(size_t)rr * SLICE_N] = h;
        if (t == T_STEPS - 1)
          out[(size_t)LAYER * (BATCH * HID) + (b0 + row) * HID + colg] = h;
      }
    }
    __syncthreads();

    // ================= stage 3: zr2 = sigma(P + h1 @ Uzr2); load g2 -> fr[0..7]
    {
      pH = loadPj(5);
      f32x4 a0 = (f32x4){0.f,0.f,0.f,0.f}, a1 = (f32x4){0.f,0.f,0.f,0.f};
      const bf16x8* ab = (const bf16x8*)h1b;
#pragma unroll
      for (int kt = 0; kt < 8; ++kt) {
        bf16x8 A = ab[kt * 64 + lane];
        a0 = mfma16(A, fr[2 * kt], a0);
        a1 = mfma16(A, fr[2 * kt + 1], a1);
        if (kt < 4) {
          fr[2 * kt]     = pg2[(2 * kt) * 64];
          fr[2 * kt + 1] = pg2[(2 * kt + 1) * 64];
        }
      }
#pragma unroll
      for (int nt = 0; nt < 2; ++nt) {
        float4 pp = nt ? pC1 : pC0;
        f32x4 ac = nt ? a1 : a0;
        if (w < 8) {
          int col = w * 32 + nt * 16 + lrow;
#pragma unroll
          for (int rr = 0; rr < 4; ++rr)
            zf[lgrp * 4 + rr][col] = 0.875f * sigm_f(ac[rr] + pp[rr]) + 0.125f;
        } else {
          int col = (w - 8) * 32 + nt * 16 + lrow;
          int fo = (col >> 3) * 16, fe = col & 7;
#pragma unroll
          for (int rr = 0; rr < 4; ++rr) {
            int row = lgrp * 4 + rr;
            float r2 = sigm_f(ac[rr] + pp[rr]);
            float h1v = __bfloat162float(h1b[(fo + row) * 8 + fe]);
            agb[(fo + row) * 8 + fe] = __float2bfloat16(r2 * h1v);
          }
        }
      }
    }
    __syncthreads();

    // ================= stage 4: g2 = tanh(P + agb @ Ug2); h2 update; load zr1(t+1) -> fr
    {
      const int last = (t == T_STEPS - 1);
      Pp += last ? 0 : PSTEP;
      pA = loadPj(0); pB = loadPj(1);
      f32x4 a2 = (f32x4){0.f,0.f,0.f,0.f};
      const bf16x8* ab = (const bf16x8*)agb;
#pragma unroll
      for (int kt = 0; kt < 8; ++kt) {
        bf16x8 A = ab[kt * 64 + lane];
        a2 = mfma16(A, fr[kt], a2);
        fr[kt]     = pz1[kt * 64];
        fr[8 + kt] = pz1[(8 + kt) * 64];
      }
#pragma unroll
      for (int rr = 0; rr < 4; ++rr) {
        int row = lgrp * 4 + rr;
        float gv = tanh_f(a2[rr] + pH[rr]);
        float z  = zf[row][colg];
        float zq = floorf(z * Q10) * IQ10;
        float h  = hreg2[rr];
        h = floorf(h * zq * Q23) * IQ23;
        h = h + rintf((1.f - z) * gv * Q23) * IQ23;
        hreg2[rr] = h;
        h2b[(fog + row) * 8 + feg] = __float2bfloat16(h);
        if (LAYER == 0)
          HseqP[(size_t)rr * HID + HALF] = __float2bfloat16(h);
        if (t == T_STEPS - 1)
          out[(size_t)LAYER * (BATCH * HID) + (b0 + row) * HID + HALF + colg] = h;
      }
      if (LAYER == 0) HseqP += (size_t)BATCH * HID;
      if (LAYER == 1 && savedP) savedP += (size_t)BATCH * SLICE_N;
    }
    __syncthreads();
  }
}

// ---------------------------------------------------------------- launch
extern "C" void kernel_launch(void* const* d_in, const int* in_sizes, int n_in,
                              void* d_out, int out_size, void* d_ws, size_t ws_size,
                              hipStream_t stream) {
  const int*   seq = (const int*)d_in[0];
  const float* emb = (const float*)d_in[1];
  AllW aw;
  for (int l = 0; l < 2; ++l)
    for (int s = 0; s < 4; ++s) {
      aw.W[l * 4 + s] = (const float*)d_in[2 + l * 8 + s * 2];
      aw.b[l * 4 + s] = (const float*)d_in[2 + l * 8 + s * 2 + 1];
    }

  uint8_t* wp = (uint8_t*)d_ws;
  float* Psw = (float*)wp;                   wp += (size_t)4 * 256 * 6 * 16 * 256 * 4; // 100.7 MB
  __hip_bfloat16* X0 = (__hip_bfloat16*)wp;  wp += (size_t)MROWS * HID * 2;            // 16.8 MB
  __hip_bfloat16* H0 = (__hip_bfloat16*)wp;  wp += (size_t)MROWS * HID * 2;            // 16.8 MB
  __hip_bfloat16* Wsw = (__hip_bfloat16*)wp; wp += (size_t)2 * FRAGS_PER_LAYER * 8 * 2;// 1.6 MB
  __hip_bfloat16* WxT = (__hip_bfloat16*)wp; wp += (size_t)2 * NCOLS * 512 * 2;        // 3.1 MB
  float* biasAll = (float*)wp;               wp += (size_t)2 * NCOLS * 4;

  float* out = (float*)d_out;

  const int prepN = (2 * FRAGS_PER_LAYER + 2 * NCOLS * 64 + 2 * NCOLS + 255) / 256;
  prep_weights<<<prepN, 256, 0, stream>>>(aw, Wsw, WxT, biasAll);
  embed_gather<<<(MROWS * 128) / 256, 256, 0, stream>>>(seq, emb, X0);

  gemm_p<<<dim3(24, 256), 256, 0, stream>>>(X0, WxT, biasAll, Psw);
  rec_kernel<0><<<4, 1024, 0, stream>>>(Wsw, Psw, out, H0);
  gemm_p<<<dim3(24, 256), 256, 0, stream>>>(H0, WxT + (size_t)NCOLS * 512, biasAll + NCOLS, Psw);
  rec_kernel<1><<<4, 1024, 0, stream>>>(Wsw + (size_t)FRAGS_PER_LAYER * 8, Psw, out, nullptr);
}

// Round 6
// 11130.922 us; speedup vs baseline: 1.2650x; 1.0394x over previous
//
#include <hip/hip_runtime.h>
#include <hip/hip_bf16.h>
#include <stdint.h>

#define T_STEPS 256
#define BATCH   64
#define HID     512
#define HALF    256
#define NCOLS   1536              // [zr1:512 | g1:256 | zr2:512 | g2:256]
#define MROWS   (T_STEPS * BATCH) // 16384
#define SLICE_N 100
#define SAVED_OFF (2 * BATCH * HID) // 65536 floats into d_out

// swizzled weight stream: per layer, 49152 fragments of 16B (8-wave tiling):
//   zr stages: frag = ((w*4+tau)*8+kt)*64+lane, cb = (tau>>1)*256+(tau&1)*16+w*32
//   g  stages: frag = ((w*2+tau)*8+kt)*64+lane, cb = w*32+tau*16
#define SB0 0
#define SB1 16384
#define SB2 24576
#define SB3 40960
#define FRAGS_PER_LAYER 49152

// P layout: [g4:4][t:256][slot:12][w:8][lane:64][rr:4] f32
//   slots 0..3 zr1 tau, 4..5 g1 tau, 6..9 zr2 tau, 10..11 g2 tau
#define PSLOT 2048              // 8*64*4 floats
#define PSTEP (12 * PSLOT)      // floats per (g4, t)

typedef short bf16x8 __attribute__((ext_vector_type(8)));
typedef float f32x4  __attribute__((ext_vector_type(4)));

__device__ __forceinline__ f32x4 mfma16(bf16x8 a, bf16x8 b, f32x4 c) {
  return __builtin_amdgcn_mfma_f32_16x16x32_bf16(a, b, c, 0, 0, 0);
}
__device__ __forceinline__ float sigm_f(float x) {
  return __builtin_amdgcn_rcpf(1.f + __expf(-x));
}
__device__ __forceinline__ float tanh_f(float x) {
  x = fminf(fmaxf(x, -30.f), 30.f);
  float e = __expf(-2.f * x);
  return (1.f - e) * __builtin_amdgcn_rcpf(1.f + e);
}

struct AllW {
  const float* W[8]; // l0: zr1,g1,zr2,g2 ; l1: zr1,g1,zr2,g2
  const float* b[8];
};

// ---------------------------------------------------------------- prep
__global__ void prep_weights(AllW aw, __hip_bfloat16* __restrict__ Wsw,
                             __hip_bfloat16* __restrict__ WxT,
                             float* __restrict__ biasAll) {
  int tid = blockIdx.x * blockDim.x + threadIdx.x;
  const int NW = 2 * FRAGS_PER_LAYER;
  const int NX = 2 * NCOLS * 64;
  if (tid < NW) {
    int l = tid / FRAGS_PER_LAYER, r = tid % FRAGS_PER_LAYER;
    int s, fi;
    if (r < SB1)      { s = 0; fi = r; }
    else if (r < SB2) { s = 1; fi = r - SB1; }
    else if (r < SB3) { s = 2; fi = r - SB2; }
    else              { s = 3; fi = r - SB3; }
    int lane = fi & 63, lrow = lane & 15, lgrp = lane >> 4;
    int zr = (s == 0 || s == 2);
    int w, tau, kt;
    if (zr) { w = fi >> 11; tau = (fi >> 9) & 3; kt = (fi >> 6) & 7; }
    else    { w = fi >> 10; tau = (fi >> 9) & 1; kt = (fi >> 6) & 7; }
    int cb = zr ? ((tau >> 1) * 256 + (tau & 1) * 16 + w * 32) : (w * 32 + tau * 16);
    const float* W = aw.W[l * 4 + s];
    int nc = zr ? 512 : 256;
    int kbase = 512 + kt * 32 + lgrp * 8;
    __hip_bfloat16 frag[8];
#pragma unroll
    for (int e = 0; e < 8; ++e)
      frag[e] = __float2bfloat16(W[(size_t)(kbase + e) * nc + cb + lrow]);
    *(uint4*)&Wsw[(size_t)tid * 8] = *(uint4*)frag;
  } else if (tid < NW + NX) {
    int u = tid - NW;
    int l = u / (NCOLS * 64), r = u % (NCOLS * 64);
    int c = r >> 6, k0 = (r & 63) * 8;
    const float* W; int nc, cc;
    if (c < 512)       { W = aw.W[l*4+0]; nc = 512; cc = c;        }
    else if (c < 768)  { W = aw.W[l*4+1]; nc = 256; cc = c - 512;  }
    else if (c < 1280) { W = aw.W[l*4+2]; nc = 512; cc = c - 768;  }
    else               { W = aw.W[l*4+3]; nc = 256; cc = c - 1280; }
    __hip_bfloat16 frag[8];
#pragma unroll
    for (int e = 0; e < 8; ++e)
      frag[e] = __float2bfloat16(W[(size_t)(k0 + e) * nc + cc]);
    *(uint4*)&WxT[((size_t)l * NCOLS + c) * 512 + k0] = *(uint4*)frag;
  } else if (tid < NW + NX + 2 * NCOLS) {
    int c = tid - NW - NX;
    int l = c / NCOLS, cc = c % NCOLS;
    const float* b; int off;
    if (cc < 512)       { b = aw.b[l*4+0]; off = cc;        }
    else if (cc < 768)  { b = aw.b[l*4+1]; off = cc - 512;  }
    else if (cc < 1280) { b = aw.b[l*4+2]; off = cc - 768;  }
    else                { b = aw.b[l*4+3]; off = cc - 1280; }
    biasAll[c] = b[off];
  }
}

// ---------------------------------------------------------------- embed gather
__global__ void embed_gather(const int* __restrict__ seq, const float* __restrict__ emb,
                             __hip_bfloat16* __restrict__ X0) {
  int i = blockIdx.x * blockDim.x + threadIdx.x; // over 16384*128
  int row = i >> 7, c4 = (i & 127) * 4;
  int idx = seq[row];
  float4 v = *(const float4*)&emb[(size_t)idx * HID + c4];
  union { __hip_bfloat16 h[4]; uint2 u; } pk;
  pk.h[0] = __float2bfloat16(v.x);
  pk.h[1] = __float2bfloat16(v.y);
  pk.h[2] = __float2bfloat16(v.z);
  pk.h[3] = __float2bfloat16(v.w);
  *(uint2*)&X0[(size_t)row * HID + c4] = pk.u;
}

// ---------------------------------------------------------------- P = A @ WxT^T + bias
__global__ __launch_bounds__(256) void gemm_p(const __hip_bfloat16* __restrict__ A,
                                              const __hip_bfloat16* __restrict__ WT,
                                              const float* __restrict__ bias,
                                              float* __restrict__ Psw) {
  const int tid = threadIdx.x;
  const int lane = tid & 63, w = tid >> 6;
  const int lrow = lane & 15, lgrp = lane >> 4;
  const int n0 = blockIdx.x * 64, m0 = blockIdx.y * 64;
  const int wm = w & 1, wn = w >> 1;
  __shared__ __hip_bfloat16 As[64][72];
  f32x4 acc[2][2];
#pragma unroll
  for (int a = 0; a < 2; ++a)
#pragma unroll
    for (int b = 0; b < 2; ++b) acc[a][b] = (f32x4){0.f, 0.f, 0.f, 0.f};

  const int lr = tid >> 2, lc = (tid & 3) * 16;
  for (int k0 = 0; k0 < 512; k0 += 64) {
    *(uint4*)&As[lr][lc]     = *(const uint4*)&A[((size_t)m0 + lr) * 512 + k0 + lc];
    *(uint4*)&As[lr][lc + 8] = *(const uint4*)&A[((size_t)m0 + lr) * 512 + k0 + lc + 8];
    __syncthreads();
#pragma unroll
    for (int kt = 0; kt < 2; ++kt) {
      bf16x8 a0 = *(const bf16x8*)&As[wm * 32 + lrow][kt * 32 + lgrp * 8];
      bf16x8 a1 = *(const bf16x8*)&As[wm * 32 + 16 + lrow][kt * 32 + lgrp * 8];
      bf16x8 b0 = *(const bf16x8*)&WT[((size_t)n0 + wn * 32 + lrow) * 512 + k0 + kt * 32 + lgrp * 8];
      bf16x8 b1 = *(const bf16x8*)&WT[((size_t)n0 + wn * 32 + 16 + lrow) * 512 + k0 + kt * 32 + lgrp * 8];
      acc[0][0] = mfma16(a0, b0, acc[0][0]);
      acc[0][1] = mfma16(a0, b1, acc[0][1]);
      acc[1][0] = mfma16(a1, b0, acc[1][0]);
      acc[1][1] = mfma16(a1, b1, acc[1][1]);
    }
    __syncthreads();
  }
  const int t = m0 >> 6;
#pragma unroll
  for (int mt = 0; mt < 2; ++mt) {
    int g = wm * 2 + mt;
#pragma unroll
    for (int nt = 0; nt < 2; ++nt) {
      int colb = n0 + wn * 32 + nt * 16; // wave-uniform
      int slot, wt;
      if (colb < 512)       { int c = colb;        wt = (c & 255) >> 5; slot = (c >> 8) * 2 + ((c >> 4) & 1); }
      else if (colb < 768)  { int c = colb - 512;  wt = c >> 5;         slot = 4 + ((c >> 4) & 1); }
      else if (colb < 1280) { int c = colb - 768;  wt = (c & 255) >> 5; slot = 6 + (c >> 8) * 2 + ((c >> 4) & 1); }
      else                  { int c = colb - 1280; wt = c >> 5;         slot = 10 + ((c >> 4) & 1); }
      float bv = bias[colb + lrow];
      float4 v;
      v.x = acc[mt][nt][0] + bv;
      v.y = acc[mt][nt][1] + bv;
      v.z = acc[mt][nt][2] + bv;
      v.w = acc[mt][nt][3] + bv;
      size_t off = (((size_t)g * 256 + t) * 12 + slot) * PSLOT + (size_t)wt * 256 + (size_t)lane * 4;
      *(float4*)&Psw[off] = v;
    }
  }
}

// ---------------------------------------------------------------- recurrence
// 4 WGs x 16 batch rows x 8 waves (512 thr). 2 waves/SIMD -> 256-reg budget;
// fb[40] rolling fragment window in ARCH VGPRs, direct global_load -> MFMA.
// Big LDS (~88KB total) forces 1 WG/CU so the compiler's occupancy heuristic
// cannot re-impose a 64-VGPR cap (the R1-R4 failure mode).
template <int LAYER>
__global__ __attribute__((amdgpu_waves_per_eu(2))) __launch_bounds__(512)
void rec_kernel(const __hip_bfloat16* __restrict__ WswL,
                const float* __restrict__ PswAll,
                float* __restrict__ out,
                __hip_bfloat16* __restrict__ Hseq) {
  const int tid = threadIdx.x;
  const int lane = tid & 63, w = tid >> 6;      // w in [0,8)
  const int lrow = lane & 15, lgrp = lane >> 4;
  const int g4 = blockIdx.x, b0 = g4 * 16;

  // bf16 A-operand buffers, fragment-major: elem(row,k) at ((k>>3)*16+row)*8+(k&7)
  __shared__ __hip_bfloat16 h1b[4096], h2b[4096], agb[4096];
  __shared__ float ldsguard[16384];  // 64KB occupancy limiter (runtime-kept)

  {
    __hip_bfloat16 z0 = __float2bfloat16(0.f);
    for (int i = tid; i < 4096; i += 512) { h1b[i] = z0; h2b[i] = z0; }
    ldsguard[tid] = (float)tid;
    if (LAYER == 1)
      for (int i = tid; i < 16 * SLICE_N; i += 512)
        out[SAVED_OFF + (size_t)(b0 + i / SLICE_N) * SLICE_N + (i % SLICE_N)] = 0.f;
  }

  const bf16x8* Wf = (const bf16x8*)WswL;
  const bf16x8* pz1 = Wf + SB0 + w * 2048 + lane;
  const bf16x8* pg1 = Wf + SB1 + w * 1024 + lane;
  const bf16x8* pz2 = Wf + SB2 + w * 2048 + lane;
  const bf16x8* pg2 = Wf + SB3 + w * 1024 + lane;

  const float* Pp = PswAll + (size_t)g4 * 256 * PSTEP + w * 256 + lane * 4;

  // master h state: thread owns rows lgrp*4+rr, cols w*32+nt*16+lrow
  float hr1[2][4] = {{0.f,0.f,0.f,0.f},{0.f,0.f,0.f,0.f}};
  float hr2[2][4] = {{0.f,0.f,0.f,0.f},{0.f,0.f,0.f,0.f}};

  bf16x8 fb[40];
#pragma unroll
  for (int i = 0; i < 32; ++i) fb[i] = pz1[i * 64];
  __syncthreads();

  const float Q23 = 8388608.f, IQ23 = 1.f / 8388608.f;
  const float Q10 = 1024.f,    IQ10 = 1.f / 1024.f;

  const int col0 = w * 32 + lrow, col1 = col0 + 16;
  const int fo0 = ((col0 >> 3) * 16 + lgrp * 4) * 8 + (col0 & 7);
  const int fo1 = ((col1 >> 3) * 16 + lgrp * 4) * 8 + (col1 & 7);

  float z1v[2][4], z2v[2][4];

  for (int t = 0; t < T_STEPS; ++t) {
    // ========== stage 1: zr1 = sigma(P + h2 @ Uzr1); fb[0..15] <- g1
    {
      float4 pS0 = *(const float4*)&Pp[0 * PSLOT];
      float4 pS1 = *(const float4*)&Pp[1 * PSLOT];
      float4 pS2 = *(const float4*)&Pp[2 * PSLOT];
      float4 pS3 = *(const float4*)&Pp[3 * PSLOT];
      f32x4 az0 = (f32x4){0.f,0.f,0.f,0.f}, az1 = az0, az2 = az0, az3 = az0;
      const bf16x8* ab = (const bf16x8*)h2b;
#pragma unroll
      for (int kt = 0; kt < 8; ++kt) {
        bf16x8 A = ab[kt * 64 + lane];
        az0 = mfma16(A, fb[kt],      az0);
        az1 = mfma16(A, fb[8 + kt],  az1);
        az2 = mfma16(A, fb[16 + kt], az2);
        az3 = mfma16(A, fb[24 + kt], az3);
        fb[kt]     = pg1[kt * 64];
        fb[8 + kt] = pg1[(8 + kt) * 64];
      }
#pragma unroll
      for (int rr = 0; rr < 4; ++rr) {
        z1v[0][rr] = 0.875f * sigm_f(az0[rr] + pS0[rr]) + 0.125f;
        z1v[1][rr] = 0.875f * sigm_f(az1[rr] + pS1[rr]) + 0.125f;
        float r10 = sigm_f(az2[rr] + pS2[rr]);
        float r11 = sigm_f(az3[rr] + pS3[rr]);
        agb[fo0 + rr * 8] = __float2bfloat16(r10 * hr2[0][rr]);
        agb[fo1 + rr * 8] = __float2bfloat16(r11 * hr2[1][rr]);
      }
    }
    __syncthreads();

    // ========== stage 2: g1 = tanh(P + agb @ Ug1); h1 update; fb[0..31] <- zr2
    {
      float4 qG0 = *(const float4*)&Pp[4 * PSLOT];
      float4 qG1 = *(const float4*)&Pp[5 * PSLOT];
      f32x4 ag0 = (f32x4){0.f,0.f,0.f,0.f}, ag1 = ag0;
      const bf16x8* ab = (const bf16x8*)agb;
#pragma unroll
      for (int kt = 0; kt < 8; ++kt) {
        bf16x8 A = ab[kt * 64 + lane];
        ag0 = mfma16(A, fb[kt],     ag0);
        ag1 = mfma16(A, fb[8 + kt], ag1);
        fb[16 + kt] = pz2[(16 + kt) * 64];
        fb[24 + kt] = pz2[(24 + kt) * 64];
        fb[kt]      = pz2[kt * 64];
        fb[8 + kt]  = pz2[(8 + kt) * 64];
      }
#pragma unroll
      for (int nt = 0; nt < 2; ++nt)
#pragma unroll
        for (int rr = 0; rr < 4; ++rr) {
          float gv = tanh_f((nt ? ag1[rr] : ag0[rr]) + (nt ? qG1[rr] : qG0[rr]));
          float z = z1v[nt][rr];
          float zq = floorf(z * Q10) * IQ10;
          float h = hr1[nt][rr];
          h = floorf(h * zq * Q23) * IQ23;
          h = h + rintf((1.f - z) * gv * Q23) * IQ23;
          hr1[nt][rr] = h;
          int fo = (nt ? fo1 : fo0) + rr * 8;
          h1b[fo] = __float2bfloat16(h);
          int col = nt ? col1 : col0;
          int row = lgrp * 4 + rr;
          if (LAYER == 0)
            Hseq[((size_t)t * BATCH + b0 + row) * HID + col] = __float2bfloat16(h);
          if (LAYER == 1 && col < SLICE_N)
            out[SAVED_OFF + (size_t)(t + 1) * (BATCH * SLICE_N) + (b0 + row) * SLICE_N + col] = h;
          if (t == T_STEPS - 1)
            out[(size_t)LAYER * (BATCH * HID) + (b0 + row) * HID + col] = h;
        }
    }
    __syncthreads();

    // ========== stage 3: zr2 = sigma(P + h1 @ Uzr2); fb[0..15] <- g2
    {
      float4 qZ0 = *(const float4*)&Pp[6 * PSLOT];
      float4 qZ1 = *(const float4*)&Pp[7 * PSLOT];
      float4 qZ2 = *(const float4*)&Pp[8 * PSLOT];
      float4 qZ3 = *(const float4*)&Pp[9 * PSLOT];
      f32x4 az0 = (f32x4){0.f,0.f,0.f,0.f}, az1 = az0, az2 = az0, az3 = az0;
      const bf16x8* ab = (const bf16x8*)h1b;
#pragma unroll
      for (int kt = 0; kt < 8; ++kt) {
        bf16x8 A = ab[kt * 64 + lane];
        az0 = mfma16(A, fb[kt],      az0);
        az1 = mfma16(A, fb[8 + kt],  az1);
        az2 = mfma16(A, fb[16 + kt], az2);
        az3 = mfma16(A, fb[24 + kt], az3);
        fb[kt]     = pg2[kt * 64];
        fb[8 + kt] = pg2[(8 + kt) * 64];
      }
#pragma unroll
      for (int rr = 0; rr < 4; ++rr) {
        z2v[0][rr] = 0.875f * sigm_f(az0[rr] + qZ0[rr]) + 0.125f;
        z2v[1][rr] = 0.875f * sigm_f(az1[rr] + qZ1[rr]) + 0.125f;
        float r20 = sigm_f(az2[rr] + qZ2[rr]);
        float r21 = sigm_f(az3[rr] + qZ3[rr]);
        agb[fo0 + rr * 8] = __float2bfloat16(r20 * hr1[0][rr]);
        agb[fo1 + rr * 8] = __float2bfloat16(r21 * hr1[1][rr]);
      }
    }
    __syncthreads();

    // ========== stage 4: g2 = tanh(P + agb @ Ug2); h2 update; fb[0..31] <- zr1(t+1)
    {
      float4 qH0 = *(const float4*)&Pp[10 * PSLOT];
      float4 qH1 = *(const float4*)&Pp[11 * PSLOT];
      if (t + 1 < T_STEPS) Pp += PSTEP;
      f32x4 ag0 = (f32x4){0.f,0.f,0.f,0.f}, ag1 = ag0;
      const bf16x8* ab = (const bf16x8*)agb;
#pragma unroll
      for (int kt = 0; kt < 8; ++kt) {
        bf16x8 A = ab[kt * 64 + lane];
        ag0 = mfma16(A, fb[kt],     ag0);
        ag1 = mfma16(A, fb[8 + kt], ag1);
        fb[16 + kt] = pz1[(16 + kt) * 64];
        fb[24 + kt] = pz1[(24 + kt) * 64];
        fb[kt]      = pz1[kt * 64];
        fb[8 + kt]  = pz1[(8 + kt) * 64];
      }
#pragma unroll
      for (int nt = 0; nt < 2; ++nt)
#pragma unroll
        for (int rr = 0; rr < 4; ++rr) {
          float gv = tanh_f((nt ? ag1[rr] : ag0[rr]) + (nt ? qH1[rr] : qH0[rr]));
          float z = z2v[nt][rr];
          float zq = floorf(z * Q10) * IQ10;
          float h = hr2[nt][rr];
          h = floorf(h * zq * Q23) * IQ23;
          h = h + rintf((1.f - z) * gv * Q23) * IQ23;
          hr2[nt][rr] = h;
          int fo = (nt ? fo1 : fo0) + rr * 8;
          h2b[fo] = __float2bfloat16(h);
          int col = nt ? col1 : col0;
          int row = lgrp * 4 + rr;
          if (LAYER == 0)
            Hseq[((size_t)t * BATCH + b0 + row) * HID + HALF + col] = __float2bfloat16(h);
          if (t == T_STEPS - 1)
            out[(size_t)LAYER * (BATCH * HID) + (b0 + row) * HID + HALF + col] = h;
        }
    }
    __syncthreads();
  }
  // keep ldsguard live (condition is never true at runtime)
  if ((uintptr_t)PswAll == 12345u) out[0] = ldsguard[lane];
}

// ---------------------------------------------------------------- launch
extern "C" void kernel_launch(void* const* d_in, const int* in_sizes, int n_in,
                              void* d_out, int out_size, void* d_ws, size_t ws_size,
                              hipStream_t stream) {
  const int*   seq = (const int*)d_in[0];
  const float* emb = (const float*)d_in[1];
  AllW aw;
  for (int l = 0; l < 2; ++l)
    for (int s = 0; s < 4; ++s) {
      aw.W[l * 4 + s] = (const float*)d_in[2 + l * 8 + s * 2];
      aw.b[l * 4 + s] = (const float*)d_in[2 + l * 8 + s * 2 + 1];
    }

  uint8_t* wp = (uint8_t*)d_ws;
  float* Psw = (float*)wp;                   wp += (size_t)4 * 256 * PSTEP * 4;        // 100.7 MB
  __hip_bfloat16* X0 = (__hip_bfloat16*)wp;  wp += (size_t)MROWS * HID * 2;            // 16.8 MB
  __hip_bfloat16* H0 = (__hip_bfloat16*)wp;  wp += (size_t)MROWS * HID * 2;            // 16.8 MB
  __hip_bfloat16* Wsw = (__hip_bfloat16*)wp; wp += (size_t)2 * FRAGS_PER_LAYER * 8 * 2;// 1.6 MB
  __hip_bfloat16* WxT = (__hip_bfloat16*)wp; wp += (size_t)2 * NCOLS * 512 * 2;        // 3.1 MB
  float* biasAll = (float*)wp;               wp += (size_t)2 * NCOLS * 4;

  float* out = (float*)d_out;

  const int prepN = (2 * FRAGS_PER_LAYER + 2 * NCOLS * 64 + 2 * NCOLS + 255) / 256;
  prep_weights<<<prepN, 256, 0, stream>>>(aw, Wsw, WxT, biasAll);
  embed_gather<<<(MROWS * 128) / 256, 256, 0, stream>>>(seq, emb, X0);

  gemm_p<<<dim3(24, 256), 256, 0, stream>>>(X0, WxT, biasAll, Psw);
  rec_kernel<0><<<4, 512, 0, stream>>>(Wsw, Psw, out, H0);
  gemm_p<<<dim3(24, 256), 256, 0, stream>>>(H0, WxT + (size_t)NCOLS * 512, biasAll + NCOLS, Psw);
  rec_kernel<1><<<4, 512, 0, stream>>>(Wsw + (size_t)FRAGS_PER_LAYER * 8, Psw, out, nullptr);
}